// Round 18
// baseline (74.712 us; speedup 1.0000x reference)
//
#include <hip/hip_runtime.h>

#define N_B   2048
#define F_SIG 1056
#define F_PAD 1088
#define K_CLS 100
#define K_PAD 128
#define KW_PAD 112         // k rows allocated in part[] (7 y-blocks x 16)
#define DROW   52          // 49 real + 3 pad, 16B-aligned rows; 52%32=20 -> conflict-benign
#define OSPLIT  8
#define OCHUNK 132
#define XW     72          // ushorts per padded-position row (16B-mult)
#define SY     64          // k_stats partial row-groups (32 rows each)
#define WF_BLKS 280        // 5 x 7 x 8
#define BF0_BLKS 128

typedef __attribute__((ext_vector_type(8))) short s8v;     // 8 bf16 in 4 VGPRs
typedef __attribute__((ext_vector_type(4))) float f4v;

__device__ __host__ __forceinline__ void split_bf16(float x, unsigned& h, unsigned& l) {
    unsigned u = __builtin_bit_cast(unsigned, x);
    unsigned hb = (u + 0x7FFFu + ((u >> 16) & 1u)) >> 16;
    float hf = __builtin_bit_cast(float, hb << 16);
    float r = x - hf;
    unsigned ur = __builtin_bit_cast(unsigned, r);
    unsigned lb = (ur + 0x7FFFu + ((ur >> 16) & 1u)) >> 16;
    h = hb & 0xFFFFu; l = lb & 0xFFFFu;
}

// ---------- prepack conv weights into MFMA A-fragments (hi/lo split) ----------
// frag f = ((tap*2+ch)*2+mt); element (lane,e): oc = mt*16+(lane&15),
// cin = ch*32+(lane>>4)*8+e, value = cw[oc][cin][tap]   (layout verified R4)
__global__ void k_wt(const float* __restrict__ cw, unsigned short* __restrict__ Ahi,
                     unsigned short* __restrict__ Alo) {
    int t = blockIdx.x * 256 + threadIdx.x;
    if (t >= 36 * 512) return;
    int f = t >> 9, r = t & 511, lane = r >> 3, e = r & 7;
    int mt = f & 1, ch = (f >> 1) & 1, tap = f >> 2;
    int oc  = mt * 16 + (lane & 15);
    int cin = ch * 32 + (lane >> 4) * 8 + e;
    float v = cw[oc * 576 + cin * 9 + tap];
    unsigned h, l;
    split_bf16(v, h, l);
    Ahi[t] = (unsigned short)h;
    Alo[t] = (unsigned short)l;
}

#define WF_FMA16(sv, vv) do { \
    A0.x = fmaf((sv).x, (vv).x, A0.x); A0.y = fmaf((sv).x, (vv).y, A0.y); \
    A0.z = fmaf((sv).x, (vv).z, A0.z); A0.w = fmaf((sv).x, (vv).w, A0.w); \
    A1.x = fmaf((sv).y, (vv).x, A1.x); A1.y = fmaf((sv).y, (vv).y, A1.y); \
    A1.z = fmaf((sv).y, (vv).z, A1.z); A1.w = fmaf((sv).y, (vv).w, A1.w); \
    A2.x = fmaf((sv).z, (vv).x, A2.x); A2.y = fmaf((sv).z, (vv).y, A2.y); \
    A2.z = fmaf((sv).z, (vv).z, A2.z); A2.w = fmaf((sv).z, (vv).w, A2.w); \
    A3.x = fmaf((sv).w, (vv).x, A3.x); A3.y = fmaf((sv).w, (vv).y, A3.y); \
    A3.z = fmaf((sv).w, (vv).z, A3.z); A3.w = fmaf((sv).w, (vv).w, A3.w); } while (0)

// ---------- FUSED: [0,280) split-K fcw@lw partials | [280,408) bf0 | [408,2456) conv+sig ----------
__launch_bounds__(256, 5)
__global__ void k_fused(const float* __restrict__ x,
                        const unsigned short* __restrict__ Ahi,
                        const unsigned short* __restrict__ Alo,
                        float* __restrict__ sig,
                        const float* __restrict__ fcw, const float* __restrict__ lw,
                        float* __restrict__ part,
                        const float* __restrict__ linb, const float* __restrict__ fcb,
                        float* __restrict__ bfv) {
    __shared__ __align__(16) unsigned short xpl[2][100 * XW];  // 28800 B
    unsigned short* xhi = xpl[0];
    unsigned short* xlo = xpl[1];
    const int tid = threadIdx.x;
    const int bid = blockIdx.x;

    if (bid < WF_BLKS) {
        // ===== k_wf body: part[z][k][i] = sum_{o in chunk z} fcw[k,o]*lin_w[o,i] =====
        const int ibx = bid % 5, ky = (bid / 5) % 7, z = bid / 35;
        const int wv = tid >> 6;
        const int k0 = ky * 16 + wv * 4;
        const int ib = ibx * 256 + (tid & 63) * 4;
        if (ib >= F_SIG) return;
        const float* f0 = fcw + (size_t)min(k0,     K_CLS - 1) * F_SIG;
        const float* f1 = fcw + (size_t)min(k0 + 1, K_CLS - 1) * F_SIG;
        const float* f2 = fcw + (size_t)min(k0 + 2, K_CLS - 1) * F_SIG;
        const float* f3 = fcw + (size_t)min(k0 + 3, K_CLS - 1) * F_SIG;
        const int o0 = z * OCHUNK;
        float4 A0 = {0.f,0.f,0.f,0.f}, A1 = {0.f,0.f,0.f,0.f};
        float4 A2 = {0.f,0.f,0.f,0.f}, A3 = {0.f,0.f,0.f,0.f};
        const float* lwb = lw + (size_t)o0 * F_SIG + ib;
        for (int g = 0; g < OCHUNK / 4; ++g) {
            const int o = o0 + g * 4;
            float4 s0 = *reinterpret_cast<const float4*>(f0 + o);
            float4 s1 = *reinterpret_cast<const float4*>(f1 + o);
            float4 s2 = *reinterpret_cast<const float4*>(f2 + o);
            float4 s3 = *reinterpret_cast<const float4*>(f3 + o);
            const float* lp = lwb + (size_t)(g * 4) * F_SIG;
            float4 v0 = *reinterpret_cast<const float4*>(lp);
            float4 v1 = *reinterpret_cast<const float4*>(lp + F_SIG);
            float4 v2 = *reinterpret_cast<const float4*>(lp + 2 * F_SIG);
            float4 v3 = *reinterpret_cast<const float4*>(lp + 3 * F_SIG);
            float4 sj0 = make_float4(s0.x, s1.x, s2.x, s3.x);
            float4 sj1 = make_float4(s0.y, s1.y, s2.y, s3.y);
            float4 sj2 = make_float4(s0.z, s1.z, s2.z, s3.z);
            float4 sj3 = make_float4(s0.w, s1.w, s2.w, s3.w);
            WF_FMA16(sj0, v0);
            WF_FMA16(sj1, v1);
            WF_FMA16(sj2, v2);
            WF_FMA16(sj3, v3);
        }
        *reinterpret_cast<float4*>(part + ((size_t)z * KW_PAD + k0 + 0) * F_SIG + ib) = A0;
        *reinterpret_cast<float4*>(part + ((size_t)z * KW_PAD + k0 + 1) * F_SIG + ib) = A1;
        *reinterpret_cast<float4*>(part + ((size_t)z * KW_PAD + k0 + 2) * F_SIG + ib) = A2;
        *reinterpret_cast<float4*>(part + ((size_t)z * KW_PAD + k0 + 3) * F_SIG + ib) = A3;
        return;
    }
    if (bid < WF_BLKS + BF0_BLKS) {
        // ===== bf0: bfv[k] = fcb[k] + sum_o fcw[k,o]*lin_b[o]  (rest added by k_wfred) =====
        const int k = bid - WF_BLKS;
        float s = 0.f;
        if (k < K_CLS) {
            const float* fr = fcw + (size_t)k * F_SIG;
            for (int o = tid; o < F_SIG; o += 256) s = fmaf(fr[o], linb[o], s);
        }
#pragma unroll
        for (int d = 32; d; d >>= 1) s += __shfl_xor(s, d);
        float* redf = (float*)xhi;
        if ((tid & 63) == 0) redf[tid >> 6] = s;
        __syncthreads();
        if (tid == 0) {
            float tot = redf[0] + redf[1] + redf[2] + redf[3];
            bfv[k] = (k < K_CLS) ? (tot + fcb[k]) : 0.f;
        }
        return;
    }

    // ===== convsig body =====
    const int b = bid - (WF_BLKS + BF0_BLKS);
    // post-conv aliases inside the (then-dead) x planes:
    float* ysT  = (float*)xpl;          // 64*36 floats = 9216 B
    float* Ds   = ysT + 2304;           // 32*52
    float* Cs   = Ds + 1664;            // 32*52
    float* colS = Cs + 1664;            // 32*8

    // border-only zero (36 pad positions x 36 words/plane); interior is fully
    // overwritten by the scatter below -> disjoint writes, no barrier needed between
    for (int e = tid; e < 1296; e += 256) {
        int bb = e / 36, w = e - bb * 36;
        int pp = (bb < 10) ? bb
               : (bb < 20) ? 90 + (bb - 10)
               : ((bb - 20) >> 1) * 10 + 10 + (((bb - 20) & 1) ? 9 : 0);
        reinterpret_cast<unsigned*>(xhi + pp * XW)[w] = 0u;
        reinterpret_cast<unsigned*>(xlo + pp * XW)[w] = 0u;
    }
    const float4* xb4 = reinterpret_cast<const float4*>(x + (size_t)b * 4096);
    {
        float4 v0 = xb4[tid], v1 = xb4[tid + 256], v2 = xb4[tid + 512], v3 = xb4[tid + 768];
#pragma unroll
        for (int u = 0; u < 4; ++u) {
            float4 v = (u == 0) ? v0 : (u == 1) ? v1 : (u == 2) ? v2 : v3;
            int e = tid + u * 256;
            int cin = e >> 4, p = (e & 15) * 4;
            int ih = p >> 3, iw = p & 7;                   // iw in {0,4}
            int pp = (ih + 1) * 10 + (iw + 1);
            unsigned h, l;
            split_bf16(v.x, h, l); xhi[(pp+0)*XW + cin] = (unsigned short)h; xlo[(pp+0)*XW + cin] = (unsigned short)l;
            split_bf16(v.y, h, l); xhi[(pp+1)*XW + cin] = (unsigned short)h; xlo[(pp+1)*XW + cin] = (unsigned short)l;
            split_bf16(v.z, h, l); xhi[(pp+2)*XW + cin] = (unsigned short)h; xlo[(pp+2)*XW + cin] = (unsigned short)l;
            split_bf16(v.w, h, l); xhi[(pp+3)*XW + cin] = (unsigned short)h; xlo[(pp+3)*XW + cin] = (unsigned short)l;
        }
    }
    __syncthreads();

    // conv: wave = (pt = pos-tile of 32, chh = cin-half). Full 32-oc x 32-pos tile,
    // 9 taps x K=32 each; per tap: 4 A-loads (both mt) + 4 B-reads + 12 MFMA.
    // chh=0 and chh=1 waves hold partials for the SAME tile -> LDS add phase below.
    // s_setprio(1) around the MFMA cluster: co-resident wf/bf0/staging waves are at
    // DIFFERENT phases (T5 prerequisite) -> conv waves win issue arbitration.
    f4v a00 = {0.f,0.f,0.f,0.f};   // [pos-tile a][mt 0]
    f4v a01 = {0.f,0.f,0.f,0.f};   // [a][mt 1]
    f4v b00 = {0.f,0.f,0.f,0.f};   // [b][0]
    f4v b01 = {0.f,0.f,0.f,0.f};   // [b][1]
    int pa_, pb_, kg_, chh_;
    {
        const int wv = tid >> 6;
        const int lane = tid & 63;
        const int j16 = lane & 15, kg = lane >> 4;
        const int pt = wv >> 1, chh = wv & 1;
        const int pa = pt * 32 + j16;
        const int pb = pa + 16;
        pa_ = pa; pb_ = pb; kg_ = kg; chh_ = chh;
        const int oha = pa >> 3, owa = pa & 7;
        const int ohb = pb >> 3, owb = pb & 7;
        const unsigned short* HbA = xhi + (oha * 10 + owa) * XW + chh * 32 + kg * 8;
        const unsigned short* LbA = xlo + (oha * 10 + owa) * XW + chh * 32 + kg * 8;
        const unsigned short* HbB = xhi + (ohb * 10 + owb) * XW + chh * 32 + kg * 8;
        const unsigned short* LbB = xlo + (ohb * 10 + owb) * XW + chh * 32 + kg * 8;
        // A-frag f = (tap*2 + chh)*2 + mt; pre-offset base by chh*2
        const uint4* AH = reinterpret_cast<const uint4*>(Ahi) + (size_t)chh * 128 + lane;
        const uint4* AL = reinterpret_cast<const uint4*>(Alo) + (size_t)chh * 128 + lane;
#pragma unroll
        for (int tap = 0; tap < 9; ++tap) {
            const int th = tap / 3, tw = tap % 3;          // fold at compile time
            const int xoff = (th * 10 + tw) * XW;
            uint4 h0 = AH[(size_t)(tap * 4) * 64];         // mt 0
            uint4 l0 = AL[(size_t)(tap * 4) * 64];
            uint4 h1 = AH[(size_t)(tap * 4 + 1) * 64];     // mt 1
            uint4 l1 = AL[(size_t)(tap * 4 + 1) * 64];
            uint4 bha = *reinterpret_cast<const uint4*>(HbA + xoff);
            uint4 bla = *reinterpret_cast<const uint4*>(LbA + xoff);
            uint4 bhb = *reinterpret_cast<const uint4*>(HbB + xoff);
            uint4 blb = *reinterpret_cast<const uint4*>(LbB + xoff);
            s8v A0h = __builtin_bit_cast(s8v, h0);
            s8v A0l = __builtin_bit_cast(s8v, l0);
            s8v A1h = __builtin_bit_cast(s8v, h1);
            s8v A1l = __builtin_bit_cast(s8v, l1);
            s8v BhA = __builtin_bit_cast(s8v, bha);
            s8v BlA = __builtin_bit_cast(s8v, bla);
            s8v BhB = __builtin_bit_cast(s8v, bhb);
            s8v BlB = __builtin_bit_cast(s8v, blb);
            __builtin_amdgcn_s_setprio(1);
            a00 = __builtin_amdgcn_mfma_f32_16x16x32_bf16(A0h, BhA, a00, 0, 0, 0);
            a00 = __builtin_amdgcn_mfma_f32_16x16x32_bf16(A0h, BlA, a00, 0, 0, 0);
            a00 = __builtin_amdgcn_mfma_f32_16x16x32_bf16(A0l, BhA, a00, 0, 0, 0);
            a01 = __builtin_amdgcn_mfma_f32_16x16x32_bf16(A1h, BhA, a01, 0, 0, 0);
            a01 = __builtin_amdgcn_mfma_f32_16x16x32_bf16(A1h, BlA, a01, 0, 0, 0);
            a01 = __builtin_amdgcn_mfma_f32_16x16x32_bf16(A1l, BhA, a01, 0, 0, 0);
            b00 = __builtin_amdgcn_mfma_f32_16x16x32_bf16(A0h, BhB, b00, 0, 0, 0);
            b00 = __builtin_amdgcn_mfma_f32_16x16x32_bf16(A0h, BlB, b00, 0, 0, 0);
            b00 = __builtin_amdgcn_mfma_f32_16x16x32_bf16(A0l, BhB, b00, 0, 0, 0);
            b01 = __builtin_amdgcn_mfma_f32_16x16x32_bf16(A1h, BhB, b01, 0, 0, 0);
            b01 = __builtin_amdgcn_mfma_f32_16x16x32_bf16(A1h, BlB, b01, 0, 0, 0);
            b01 = __builtin_amdgcn_mfma_f32_16x16x32_bf16(A1l, BhB, b01, 0, 0, 0);
            __builtin_amdgcn_s_setprio(0);
        }
    }
    __syncthreads();   // all x-plane reads done; planes now dead
    // C/D: col=lane&15 -> position within tile, row=(lane>>4)*4+reg -> oc within 16
    if (chh_ == 0) {
        *reinterpret_cast<f4v*>(ysT + pa_ * 36 + kg_ * 4)      = a00;
        *reinterpret_cast<f4v*>(ysT + pa_ * 36 + 16 + kg_ * 4) = a01;
        *reinterpret_cast<f4v*>(ysT + pb_ * 36 + kg_ * 4)      = b00;
        *reinterpret_cast<f4v*>(ysT + pb_ * 36 + 16 + kg_ * 4) = b01;
    }
    __syncthreads();
    if (chh_ == 1) {
        f4v* p0 = reinterpret_cast<f4v*>(ysT + pa_ * 36 + kg_ * 4);
        f4v* p1 = reinterpret_cast<f4v*>(ysT + pa_ * 36 + 16 + kg_ * 4);
        f4v* p2 = reinterpret_cast<f4v*>(ysT + pb_ * 36 + kg_ * 4);
        f4v* p3 = reinterpret_cast<f4v*>(ysT + pb_ * 36 + 16 + kg_ * 4);
        *p0 += a00; *p1 += a01; *p2 += b00; *p3 += b01;
    }
    __syncthreads();

    // fused D + strict column scan; thread = (c, j)
    if (tid < 224) {
        const int c = tid / 7, j = tid - (tid / 7) * 7;
        float a  = ysT[j * 36 + c];
        float bq = ysT[(j + 1) * 36 + c];
        float run = 0.f;
        float* Dc = Ds + c * DROW;
        float* Cc = Cs + c * DROW;
#pragma unroll
        for (int i = 0; i < 7; ++i) {
            float a2 = ysT[((i + 1) * 8 + j) * 36 + c];
            float b2 = ysT[((i + 1) * 8 + j + 1) * 36 + c];
            float d = (b2 - a2) - (bq - a);
            Dc[i * 7 + j] = d;
            Cc[i * 7 + j] = run;
            run += d;
            a = a2; bq = b2;
        }
        colS[c * 8 + j] = run;
    } else {
        const int c = tid - 224;
        Ds[c * DROW + 49] = 0.f; Ds[c * DROW + 50] = 0.f; Ds[c * DROW + 51] = 0.f;
    }
    __syncthreads();

    // in-place strict row scan
    if (tid < 224) {
        const int c = tid / 7, i = tid - (tid / 7) * 7;
        float* Cc = Cs + c * DROW + i * 7;
        float run = 0.f;
#pragma unroll
        for (int j = 0; j < 7; ++j) {
            float v = Cc[j];
            Cc[j] = run;
            run += v;
        }
    } else {
        const int c = tid - 224;
        Cs[c * DROW + 49] = 0.f; Cs[c * DROW + 50] = 0.f; Cs[c * DROW + 51] = 0.f;
    }
    __syncthreads();

    // level-2: 2x2 register-blocked, vectorized LDS reads (P = Cs)
    {
        const int bc1 = tid >> 4, bc2 = tid & 15;
        const float* P0 = Cs + bc1 * DROW;
        const float* P1 = Cs + (bc1 + 16) * DROW;
        const float* D0 = Ds + bc2 * DROW;
        const float* D1 = Ds + (bc2 + 16) * DROW;
        float a00v = 0.f, a01v = 0.f, a10v = 0.f, a11v = 0.f;
#pragma unroll
        for (int qb = 0; qb < DROW; qb += 4) {
            float4 p0 = *reinterpret_cast<const float4*>(P0 + qb);
            float4 p1 = *reinterpret_cast<const float4*>(P1 + qb);
            float4 d0 = *reinterpret_cast<const float4*>(D0 + qb);
            float4 d1 = *reinterpret_cast<const float4*>(D1 + qb);
            a00v += p0.x*d0.x + p0.y*d0.y + p0.z*d0.z + p0.w*d0.w;
            a01v += p0.x*d1.x + p0.y*d1.y + p0.z*d1.z + p0.w*d1.w;
            a10v += p1.x*d0.x + p1.y*d0.y + p1.z*d0.z + p1.w*d0.w;
            a11v += p1.x*d1.x + p1.y*d1.y + p1.z*d1.z + p1.w*d1.w;
        }
        float* so = sig + (size_t)b * F_PAD + 32;
        so[bc1 * 32 + bc2]               = a00v;
        so[bc1 * 32 + (bc2 + 16)]        = a01v;
        so[(bc1 + 16) * 32 + bc2]        = a10v;
        so[(bc1 + 16) * 32 + (bc2 + 16)] = a11v;
    }

    // level-1 + zero pad
    if (tid < 32) {
        const float* cr = colS + tid * 8;
        float s = cr[0] + cr[1] + cr[2] + cr[3] + cr[4] + cr[5] + cr[6];
        sig[(size_t)b * F_PAD + tid] = s;
    } else if (tid < 64) {
        sig[(size_t)b * F_PAD + F_SIG + (tid - 32)] = 0.f;
    }
}

// ---------- per-feature partial sum / sumsq (no atomics, no init, 8-row ILP, 32 rows) ----------
__global__ void k_stats(const float* __restrict__ sig, float* __restrict__ psum,
                        float* __restrict__ psq) {
    int f = blockIdx.x * 256 + threadIdx.x;
    if (f >= F_SIG) return;
    int y = blockIdx.y;
    const float* sp = sig + (size_t)(y * 32) * F_PAD + f;
    float s = 0.f, q = 0.f;
    for (int r = 0; r < 32; r += 8) {
        float v0 = sp[(size_t)(r + 0) * F_PAD];
        float v1 = sp[(size_t)(r + 1) * F_PAD];
        float v2 = sp[(size_t)(r + 2) * F_PAD];
        float v3 = sp[(size_t)(r + 3) * F_PAD];
        float v4 = sp[(size_t)(r + 4) * F_PAD];
        float v5 = sp[(size_t)(r + 5) * F_PAD];
        float v6 = sp[(size_t)(r + 6) * F_PAD];
        float v7 = sp[(size_t)(r + 7) * F_PAD];
        s += v0 + v1 + v2 + v3 + v4 + v5 + v6 + v7;
        q = fmaf(v0, v0, q); q = fmaf(v1, v1, q);
        q = fmaf(v2, v2, q); q = fmaf(v3, v3, q);
        q = fmaf(v4, v4, q); q = fmaf(v5, v5, q);
        q = fmaf(v6, v6, q); q = fmaf(v7, v7, q);
    }
    psum[(size_t)y * F_PAD + f] = s;
    psq[(size_t)y * F_PAD + f]  = q;
}

// ---------- reduce partials + inline BN fold; WfT + bias accumulation ----------
__launch_bounds__(64)
__global__ void k_wfred(const float* __restrict__ part,
                        const float* __restrict__ psum, const float* __restrict__ psq,
                        const float* __restrict__ gamma, const float* __restrict__ beta,
                        float* __restrict__ WfT, float* __restrict__ bfv) {
    const int i = blockIdx.x * 64 + threadIdx.x;
    const int k = blockIdx.y;
    float a = 0.f, bb = 0.f;
    if (i < F_SIG) {
        float s = 0.f, q = 0.f;
#pragma unroll
        for (int z = 0; z < SY; ++z) {
            s += psum[(size_t)z * F_PAD + i];
            q += psq[(size_t)z * F_PAD + i];
        }
        float m   = s * (1.f / 2048.f);
        float var = q * (1.f / 2048.f) - m * m;
        a  = gamma[i] / sqrtf(var + 1e-5f);
        bb = beta[i] - m * a;
    }
    const bool valid = (i < F_SIG) && (k < K_CLS);
    float s = 0.f;
    if (valid) {
#pragma unroll
        for (int z = 0; z < OSPLIT; ++z)
            s += part[((size_t)z * KW_PAD + k) * F_SIG + i];
    }
    if (i < F_SIG)
        WfT[(size_t)i * K_PAD + k] = valid ? a * s : 0.f;
    float pb = valid ? bb * s : 0.f;
#pragma unroll
    for (int d = 32; d; d >>= 1) pb += __shfl_xor(pb, d);
    if (threadIdx.x == 0 && k < K_CLS) atomicAdd(&bfv[k], pb);
}

// ---------- out[r,k]: 8 rows/block, waves split i-range; red aliases slT (33.8 KB LDS) ----------
__launch_bounds__(256, 4)
__global__ void k_out3(const float* __restrict__ sig, const float* __restrict__ WfT,
                       const float* __restrict__ bf, float* __restrict__ out) {
    __shared__ __align__(16) float slT[F_SIG * 8];   // [i][row]; later aliased as red[4096]
    const int tid = threadIdx.x;
    const int r0 = blockIdx.x * 8;
    for (int e = tid; e < 8 * (F_SIG / 4); e += 256) {
        int row = e & 7, c4 = e >> 3;
        float4 v = *reinterpret_cast<const float4*>(sig + (size_t)(r0 + row) * F_PAD + c4 * 4);
        slT[(c4 * 4 + 0) * 8 + row] = v.x;
        slT[(c4 * 4 + 1) * 8 + row] = v.y;
        slT[(c4 * 4 + 2) * 8 + row] = v.z;
        slT[(c4 * 4 + 3) * 8 + row] = v.w;
    }
    __syncthreads();

    const int wv = tid >> 6, lane = tid & 63;
    const int i0 = wv * 264;
    const float2* Wp = reinterpret_cast<const float2*>(WfT) + lane;
    float2 acc[8];
#pragma unroll
    for (int r = 0; r < 8; ++r) acc[r] = make_float2(0.f, 0.f);
    for (int g = 0; g < 33; ++g) {
        const int ib = i0 + g * 8;
        float2 w0 = Wp[(size_t)(ib + 0) * 64];
        float2 w1 = Wp[(size_t)(ib + 1) * 64];
        float2 w2 = Wp[(size_t)(ib + 2) * 64];
        float2 w3 = Wp[(size_t)(ib + 3) * 64];
        float2 w4 = Wp[(size_t)(ib + 4) * 64];
        float2 w5 = Wp[(size_t)(ib + 5) * 64];
        float2 w6 = Wp[(size_t)(ib + 6) * 64];
        float2 w7 = Wp[(size_t)(ib + 7) * 64];
#pragma unroll
        for (int j = 0; j < 8; ++j) {
            float2 wj = (j == 0) ? w0 : (j == 1) ? w1 : (j == 2) ? w2 : (j == 3) ? w3
                      : (j == 4) ? w4 : (j == 5) ? w5 : (j == 6) ? w6 : w7;
            const float4* sp = reinterpret_cast<const float4*>(slT + (ib + j) * 8);
            float4 ra = sp[0], rb = sp[1];
            acc[0].x = fmaf(ra.x, wj.x, acc[0].x); acc[0].y = fmaf(ra.x, wj.y, acc[0].y);
            acc[1].x = fmaf(ra.y, wj.x, acc[1].x); acc[1].y = fmaf(ra.y, wj.y, acc[1].y);
            acc[2].x = fmaf(ra.z, wj.x, acc[2].x); acc[2].y = fmaf(ra.z, wj.y, acc[2].y);
            acc[3].x = fmaf(ra.w, wj.x, acc[3].x); acc[3].y = fmaf(ra.w, wj.y, acc[3].y);
            acc[4].x = fmaf(rb.x, wj.x, acc[4].x); acc[4].y = fmaf(rb.x, wj.y, acc[4].y);
            acc[5].x = fmaf(rb.y, wj.x, acc[5].x); acc[5].y = fmaf(rb.y, wj.y, acc[5].y);
            acc[6].x = fmaf(rb.z, wj.x, acc[6].x); acc[6].y = fmaf(rb.z, wj.y, acc[6].y);
            acc[7].x = fmaf(rb.w, wj.x, acc[7].x); acc[7].y = fmaf(rb.w, wj.y, acc[7].y);
        }
    }
    __syncthreads();                      // all slT reads done -> safe to alias as red
    float* red = slT;
    float2* rp = reinterpret_cast<float2*>(red) + wv * 512 + lane;
#pragma unroll
    for (int r = 0; r < 8; ++r) rp[r * 64] = acc[r];
    __syncthreads();
#pragma unroll
    for (int j = 0; j < 4; ++j) {
        int idx = j * 256 + tid;
        int r = idx >> 7, k = idx & 127;
        float s = red[idx] + red[idx + 1024] + red[idx + 2048] + red[idx + 3072];
        if (k < K_CLS) out[(size_t)(r0 + r) * K_CLS + k] = s + bf[k];
    }
}

extern "C" void kernel_launch(void* const* d_in, const int* in_sizes, int n_in,
                              void* d_out, int out_size, void* d_ws, size_t ws_size,
                              hipStream_t stream) {
    (void)in_sizes; (void)n_in; (void)out_size; (void)ws_size;
    const float* feats = (const float*)d_in[0];
    const float* convw = (const float*)d_in[1];
    const float* gamma = (const float*)d_in[2];
    const float* beta  = (const float*)d_in[3];
    const float* linw  = (const float*)d_in[4];
    const float* linb  = (const float*)d_in[5];
    const float* fcw   = (const float*)d_in[6];
    const float* fcb   = (const float*)d_in[7];
    float* out = (float*)d_out;

    float* ws   = (float*)d_ws;
    float* sig  = ws;                                   // 2048*1088
    float* psum = sig + (size_t)N_B * F_PAD;            // 64*1088
    float* psq  = psum + (size_t)SY * F_PAD;            // 64*1088
    float* part = psq + (size_t)SY * F_PAD;             // 8*112*1056
    float* WfT  = part + (size_t)OSPLIT * KW_PAD * F_SIG;// 1056*128
    float* bfv  = WfT + (size_t)F_SIG * K_PAD;          // 128
    unsigned short* Ahi = (unsigned short*)(bfv + K_PAD);   // 36*512 ushort
    unsigned short* Alo = Ahi + 36 * 512;

    k_wt<<<72, 256, 0, stream>>>(convw, Ahi, Alo);
    k_fused<<<WF_BLKS + BF0_BLKS + N_B, 256, 0, stream>>>(feats, Ahi, Alo, sig,
                                                          fcw, linw, part, linb, fcb, bfv);
    k_stats<<<dim3(5, SY), 256, 0, stream>>>(sig, psum, psq);
    k_wfred<<<dim3(17, K_PAD), 64, 0, stream>>>(part, psum, psq, gamma, beta, WfT, bfv);
    k_out3<<<N_B / 8, 256, 0, stream>>>(sig, WfT, bfv, out);
}

// Round 19
// 71.575 us; speedup vs baseline: 1.0438x; 1.0438x over previous
//
#include <hip/hip_runtime.h>

#define N_B   2048
#define F_SIG 1056
#define F_PAD 1088
#define K_CLS 100
#define K_PAD 128
#define KW_PAD 112         // k rows allocated in part[] (7 y-blocks x 16)
#define DROW   52          // 49 real + 3 pad, 16B-aligned rows; 52%32=20 -> conflict-benign
#define OSPLIT  8
#define OCHUNK 132
#define XW     72          // ushorts per padded-position row (16B-mult)
#define SY     32          // k_stats partial row-groups (64 rows each)
#define WF_BLKS 280        // 5 x 7 x 8
#define BF0_BLKS 128

typedef __attribute__((ext_vector_type(8))) short s8v;     // 8 bf16 in 4 VGPRs
typedef __attribute__((ext_vector_type(4))) float f4v;

__device__ __host__ __forceinline__ void split_bf16(float x, unsigned& h, unsigned& l) {
    unsigned u = __builtin_bit_cast(unsigned, x);
    unsigned hb = (u + 0x7FFFu + ((u >> 16) & 1u)) >> 16;
    float hf = __builtin_bit_cast(float, hb << 16);
    float r = x - hf;
    unsigned ur = __builtin_bit_cast(unsigned, r);
    unsigned lb = (ur + 0x7FFFu + ((ur >> 16) & 1u)) >> 16;
    h = hb & 0xFFFFu; l = lb & 0xFFFFu;
}

// ---------- prepack conv weights into MFMA A-fragments (hi/lo split) ----------
// frag f = ((tap*2+ch)*2+mt); element (lane,e): oc = mt*16+(lane&15),
// cin = ch*32+(lane>>4)*8+e, value = cw[oc][cin][tap]   (layout verified R4)
__global__ void k_wt(const float* __restrict__ cw, unsigned short* __restrict__ Ahi,
                     unsigned short* __restrict__ Alo) {
    int t = blockIdx.x * 256 + threadIdx.x;
    if (t >= 36 * 512) return;
    int f = t >> 9, r = t & 511, lane = r >> 3, e = r & 7;
    int mt = f & 1, ch = (f >> 1) & 1, tap = f >> 2;
    int oc  = mt * 16 + (lane & 15);
    int cin = ch * 32 + (lane >> 4) * 8 + e;
    float v = cw[oc * 576 + cin * 9 + tap];
    unsigned h, l;
    split_bf16(v, h, l);
    Ahi[t] = (unsigned short)h;
    Alo[t] = (unsigned short)l;
}

#define WF_FMA16(sv, vv) do { \
    A0.x = fmaf((sv).x, (vv).x, A0.x); A0.y = fmaf((sv).x, (vv).y, A0.y); \
    A0.z = fmaf((sv).x, (vv).z, A0.z); A0.w = fmaf((sv).x, (vv).w, A0.w); \
    A1.x = fmaf((sv).y, (vv).x, A1.x); A1.y = fmaf((sv).y, (vv).y, A1.y); \
    A1.z = fmaf((sv).y, (vv).z, A1.z); A1.w = fmaf((sv).y, (vv).w, A1.w); \
    A2.x = fmaf((sv).z, (vv).x, A2.x); A2.y = fmaf((sv).z, (vv).y, A2.y); \
    A2.z = fmaf((sv).z, (vv).z, A2.z); A2.w = fmaf((sv).z, (vv).w, A2.w); \
    A3.x = fmaf((sv).w, (vv).x, A3.x); A3.y = fmaf((sv).w, (vv).y, A3.y); \
    A3.z = fmaf((sv).w, (vv).z, A3.z); A3.w = fmaf((sv).w, (vv).w, A3.w); } while (0)

// ---------- FUSED: [0,280) split-K fcw@lw partials | [280,408) bf0 | [408,2456) conv+sig ----------
__launch_bounds__(256, 5)
__global__ void k_fused(const float* __restrict__ x,
                        const unsigned short* __restrict__ Ahi,
                        const unsigned short* __restrict__ Alo,
                        float* __restrict__ sig,
                        const float* __restrict__ fcw, const float* __restrict__ lw,
                        float* __restrict__ part,
                        const float* __restrict__ linb, const float* __restrict__ fcb,
                        float* __restrict__ bfv) {
    __shared__ __align__(16) unsigned short xpl[2][100 * XW];  // 28800 B
    unsigned short* xhi = xpl[0];
    unsigned short* xlo = xpl[1];
    const int tid = threadIdx.x;
    const int bid = blockIdx.x;

    if (bid < WF_BLKS) {
        // ===== k_wf body: part[z][k][i] = sum_{o in chunk z} fcw[k,o]*lin_w[o,i] =====
        const int ibx = bid % 5, ky = (bid / 5) % 7, z = bid / 35;
        const int wv = tid >> 6;
        const int k0 = ky * 16 + wv * 4;
        const int ib = ibx * 256 + (tid & 63) * 4;
        if (ib >= F_SIG) return;
        const float* f0 = fcw + (size_t)min(k0,     K_CLS - 1) * F_SIG;
        const float* f1 = fcw + (size_t)min(k0 + 1, K_CLS - 1) * F_SIG;
        const float* f2 = fcw + (size_t)min(k0 + 2, K_CLS - 1) * F_SIG;
        const float* f3 = fcw + (size_t)min(k0 + 3, K_CLS - 1) * F_SIG;
        const int o0 = z * OCHUNK;
        float4 A0 = {0.f,0.f,0.f,0.f}, A1 = {0.f,0.f,0.f,0.f};
        float4 A2 = {0.f,0.f,0.f,0.f}, A3 = {0.f,0.f,0.f,0.f};
        const float* lwb = lw + (size_t)o0 * F_SIG + ib;
        for (int g = 0; g < OCHUNK / 4; ++g) {
            const int o = o0 + g * 4;
            float4 s0 = *reinterpret_cast<const float4*>(f0 + o);
            float4 s1 = *reinterpret_cast<const float4*>(f1 + o);
            float4 s2 = *reinterpret_cast<const float4*>(f2 + o);
            float4 s3 = *reinterpret_cast<const float4*>(f3 + o);
            const float* lp = lwb + (size_t)(g * 4) * F_SIG;
            float4 v0 = *reinterpret_cast<const float4*>(lp);
            float4 v1 = *reinterpret_cast<const float4*>(lp + F_SIG);
            float4 v2 = *reinterpret_cast<const float4*>(lp + 2 * F_SIG);
            float4 v3 = *reinterpret_cast<const float4*>(lp + 3 * F_SIG);
            float4 sj0 = make_float4(s0.x, s1.x, s2.x, s3.x);
            float4 sj1 = make_float4(s0.y, s1.y, s2.y, s3.y);
            float4 sj2 = make_float4(s0.z, s1.z, s2.z, s3.z);
            float4 sj3 = make_float4(s0.w, s1.w, s2.w, s3.w);
            WF_FMA16(sj0, v0);
            WF_FMA16(sj1, v1);
            WF_FMA16(sj2, v2);
            WF_FMA16(sj3, v3);
        }
        *reinterpret_cast<float4*>(part + ((size_t)z * KW_PAD + k0 + 0) * F_SIG + ib) = A0;
        *reinterpret_cast<float4*>(part + ((size_t)z * KW_PAD + k0 + 1) * F_SIG + ib) = A1;
        *reinterpret_cast<float4*>(part + ((size_t)z * KW_PAD + k0 + 2) * F_SIG + ib) = A2;
        *reinterpret_cast<float4*>(part + ((size_t)z * KW_PAD + k0 + 3) * F_SIG + ib) = A3;
        return;
    }
    if (bid < WF_BLKS + BF0_BLKS) {
        // ===== bf0: bfv[k] = fcb[k] + sum_o fcw[k,o]*lin_b[o]  (rest added by k_wfred) =====
        const int k = bid - WF_BLKS;
        float s = 0.f;
        if (k < K_CLS) {
            const float* fr = fcw + (size_t)k * F_SIG;
            for (int o = tid; o < F_SIG; o += 256) s = fmaf(fr[o], linb[o], s);
        }
#pragma unroll
        for (int d = 32; d; d >>= 1) s += __shfl_xor(s, d);
        float* redf = (float*)xhi;
        if ((tid & 63) == 0) redf[tid >> 6] = s;
        __syncthreads();
        if (tid == 0) {
            float tot = redf[0] + redf[1] + redf[2] + redf[3];
            bfv[k] = (k < K_CLS) ? (tot + fcb[k]) : 0.f;
        }
        return;
    }

    // ===== convsig body =====
    const int b = bid - (WF_BLKS + BF0_BLKS);
    // post-conv aliases inside the (then-dead) x planes:
    float* ysT  = (float*)xpl;          // 64*36 floats = 9216 B
    float* Ds   = ysT + 2304;           // 32*52
    float* Cs   = Ds + 1664;            // 32*52
    float* colS = Cs + 1664;            // 32*8

    // border-only zero (36 pad positions x 36 words/plane); interior is fully
    // overwritten by the scatter below -> disjoint writes, no barrier needed between
    for (int e = tid; e < 1296; e += 256) {
        int bb = e / 36, w = e - bb * 36;
        int pp = (bb < 10) ? bb
               : (bb < 20) ? 90 + (bb - 10)
               : ((bb - 20) >> 1) * 10 + 10 + (((bb - 20) & 1) ? 9 : 0);
        reinterpret_cast<unsigned*>(xhi + pp * XW)[w] = 0u;
        reinterpret_cast<unsigned*>(xlo + pp * XW)[w] = 0u;
    }
    const float4* xb4 = reinterpret_cast<const float4*>(x + (size_t)b * 4096);
    {
        float4 v0 = xb4[tid], v1 = xb4[tid + 256], v2 = xb4[tid + 512], v3 = xb4[tid + 768];
#pragma unroll
        for (int u = 0; u < 4; ++u) {
            float4 v = (u == 0) ? v0 : (u == 1) ? v1 : (u == 2) ? v2 : v3;
            int e = tid + u * 256;
            int cin = e >> 4, p = (e & 15) * 4;
            int ih = p >> 3, iw = p & 7;                   // iw in {0,4}
            int pp = (ih + 1) * 10 + (iw + 1);
            unsigned h, l;
            split_bf16(v.x, h, l); xhi[(pp+0)*XW + cin] = (unsigned short)h; xlo[(pp+0)*XW + cin] = (unsigned short)l;
            split_bf16(v.y, h, l); xhi[(pp+1)*XW + cin] = (unsigned short)h; xlo[(pp+1)*XW + cin] = (unsigned short)l;
            split_bf16(v.z, h, l); xhi[(pp+2)*XW + cin] = (unsigned short)h; xlo[(pp+2)*XW + cin] = (unsigned short)l;
            split_bf16(v.w, h, l); xhi[(pp+3)*XW + cin] = (unsigned short)h; xlo[(pp+3)*XW + cin] = (unsigned short)l;
        }
    }
    __syncthreads();

    // conv: wave = (pt = pos-tile of 32, chh = cin-half). Full 32-oc x 32-pos tile,
    // 9 taps x K=32 each; per tap: 4 A-loads (both mt) + 4 B-reads + 12 MFMA.
    // chh=0 and chh=1 waves hold partials for the SAME tile -> LDS add phase below.
    f4v a00 = {0.f,0.f,0.f,0.f};   // [pos-tile a][mt 0]
    f4v a01 = {0.f,0.f,0.f,0.f};   // [a][mt 1]
    f4v b00 = {0.f,0.f,0.f,0.f};   // [b][0]
    f4v b01 = {0.f,0.f,0.f,0.f};   // [b][1]
    int pa_, pb_, kg_, chh_;
    {
        const int wv = tid >> 6;
        const int lane = tid & 63;
        const int j16 = lane & 15, kg = lane >> 4;
        const int pt = wv >> 1, chh = wv & 1;
        const int pa = pt * 32 + j16;
        const int pb = pa + 16;
        pa_ = pa; pb_ = pb; kg_ = kg; chh_ = chh;
        const int oha = pa >> 3, owa = pa & 7;
        const int ohb = pb >> 3, owb = pb & 7;
        const unsigned short* HbA = xhi + (oha * 10 + owa) * XW + chh * 32 + kg * 8;
        const unsigned short* LbA = xlo + (oha * 10 + owa) * XW + chh * 32 + kg * 8;
        const unsigned short* HbB = xhi + (ohb * 10 + owb) * XW + chh * 32 + kg * 8;
        const unsigned short* LbB = xlo + (ohb * 10 + owb) * XW + chh * 32 + kg * 8;
        // A-frag f = (tap*2 + chh)*2 + mt; pre-offset base by chh*2
        const uint4* AH = reinterpret_cast<const uint4*>(Ahi) + (size_t)chh * 128 + lane;
        const uint4* AL = reinterpret_cast<const uint4*>(Alo) + (size_t)chh * 128 + lane;
#pragma unroll
        for (int tap = 0; tap < 9; ++tap) {
            const int th = tap / 3, tw = tap % 3;          // fold at compile time
            const int xoff = (th * 10 + tw) * XW;
            uint4 h0 = AH[(size_t)(tap * 4) * 64];         // mt 0
            uint4 l0 = AL[(size_t)(tap * 4) * 64];
            uint4 h1 = AH[(size_t)(tap * 4 + 1) * 64];     // mt 1
            uint4 l1 = AL[(size_t)(tap * 4 + 1) * 64];
            uint4 bha = *reinterpret_cast<const uint4*>(HbA + xoff);
            uint4 bla = *reinterpret_cast<const uint4*>(LbA + xoff);
            uint4 bhb = *reinterpret_cast<const uint4*>(HbB + xoff);
            uint4 blb = *reinterpret_cast<const uint4*>(LbB + xoff);
            s8v A0h = __builtin_bit_cast(s8v, h0);
            s8v A0l = __builtin_bit_cast(s8v, l0);
            s8v A1h = __builtin_bit_cast(s8v, h1);
            s8v A1l = __builtin_bit_cast(s8v, l1);
            s8v BhA = __builtin_bit_cast(s8v, bha);
            s8v BlA = __builtin_bit_cast(s8v, bla);
            s8v BhB = __builtin_bit_cast(s8v, bhb);
            s8v BlB = __builtin_bit_cast(s8v, blb);
            a00 = __builtin_amdgcn_mfma_f32_16x16x32_bf16(A0h, BhA, a00, 0, 0, 0);
            a00 = __builtin_amdgcn_mfma_f32_16x16x32_bf16(A0h, BlA, a00, 0, 0, 0);
            a00 = __builtin_amdgcn_mfma_f32_16x16x32_bf16(A0l, BhA, a00, 0, 0, 0);
            a01 = __builtin_amdgcn_mfma_f32_16x16x32_bf16(A1h, BhA, a01, 0, 0, 0);
            a01 = __builtin_amdgcn_mfma_f32_16x16x32_bf16(A1h, BlA, a01, 0, 0, 0);
            a01 = __builtin_amdgcn_mfma_f32_16x16x32_bf16(A1l, BhA, a01, 0, 0, 0);
            b00 = __builtin_amdgcn_mfma_f32_16x16x32_bf16(A0h, BhB, b00, 0, 0, 0);
            b00 = __builtin_amdgcn_mfma_f32_16x16x32_bf16(A0h, BlB, b00, 0, 0, 0);
            b00 = __builtin_amdgcn_mfma_f32_16x16x32_bf16(A0l, BhB, b00, 0, 0, 0);
            b01 = __builtin_amdgcn_mfma_f32_16x16x32_bf16(A1h, BhB, b01, 0, 0, 0);
            b01 = __builtin_amdgcn_mfma_f32_16x16x32_bf16(A1h, BlB, b01, 0, 0, 0);
            b01 = __builtin_amdgcn_mfma_f32_16x16x32_bf16(A1l, BhB, b01, 0, 0, 0);
        }
    }
    __syncthreads();   // all x-plane reads done; planes now dead
    // C/D: col=lane&15 -> position within tile, row=(lane>>4)*4+reg -> oc within 16
    if (chh_ == 0) {
        *reinterpret_cast<f4v*>(ysT + pa_ * 36 + kg_ * 4)      = a00;
        *reinterpret_cast<f4v*>(ysT + pa_ * 36 + 16 + kg_ * 4) = a01;
        *reinterpret_cast<f4v*>(ysT + pb_ * 36 + kg_ * 4)      = b00;
        *reinterpret_cast<f4v*>(ysT + pb_ * 36 + 16 + kg_ * 4) = b01;
    }
    __syncthreads();
    if (chh_ == 1) {
        f4v* p0 = reinterpret_cast<f4v*>(ysT + pa_ * 36 + kg_ * 4);
        f4v* p1 = reinterpret_cast<f4v*>(ysT + pa_ * 36 + 16 + kg_ * 4);
        f4v* p2 = reinterpret_cast<f4v*>(ysT + pb_ * 36 + kg_ * 4);
        f4v* p3 = reinterpret_cast<f4v*>(ysT + pb_ * 36 + 16 + kg_ * 4);
        *p0 += a00; *p1 += a01; *p2 += b00; *p3 += b01;
    }
    __syncthreads();

    // fused D + strict column scan; thread = (c, j)
    if (tid < 224) {
        const int c = tid / 7, j = tid - (tid / 7) * 7;
        float a  = ysT[j * 36 + c];
        float bq = ysT[(j + 1) * 36 + c];
        float run = 0.f;
        float* Dc = Ds + c * DROW;
        float* Cc = Cs + c * DROW;
#pragma unroll
        for (int i = 0; i < 7; ++i) {
            float a2 = ysT[((i + 1) * 8 + j) * 36 + c];
            float b2 = ysT[((i + 1) * 8 + j + 1) * 36 + c];
            float d = (b2 - a2) - (bq - a);
            Dc[i * 7 + j] = d;
            Cc[i * 7 + j] = run;
            run += d;
            a = a2; bq = b2;
        }
        colS[c * 8 + j] = run;
    } else {
        const int c = tid - 224;
        Ds[c * DROW + 49] = 0.f; Ds[c * DROW + 50] = 0.f; Ds[c * DROW + 51] = 0.f;
    }
    __syncthreads();

    // in-place strict row scan
    if (tid < 224) {
        const int c = tid / 7, i = tid - (tid / 7) * 7;
        float* Cc = Cs + c * DROW + i * 7;
        float run = 0.f;
#pragma unroll
        for (int j = 0; j < 7; ++j) {
            float v = Cc[j];
            Cc[j] = run;
            run += v;
        }
    } else {
        const int c = tid - 224;
        Cs[c * DROW + 49] = 0.f; Cs[c * DROW + 50] = 0.f; Cs[c * DROW + 51] = 0.f;
    }
    __syncthreads();

    // level-2: 2x2 register-blocked, vectorized LDS reads (P = Cs)
    {
        const int bc1 = tid >> 4, bc2 = tid & 15;
        const float* P0 = Cs + bc1 * DROW;
        const float* P1 = Cs + (bc1 + 16) * DROW;
        const float* D0 = Ds + bc2 * DROW;
        const float* D1 = Ds + (bc2 + 16) * DROW;
        float a00v = 0.f, a01v = 0.f, a10v = 0.f, a11v = 0.f;
#pragma unroll
        for (int qb = 0; qb < DROW; qb += 4) {
            float4 p0 = *reinterpret_cast<const float4*>(P0 + qb);
            float4 p1 = *reinterpret_cast<const float4*>(P1 + qb);
            float4 d0 = *reinterpret_cast<const float4*>(D0 + qb);
            float4 d1 = *reinterpret_cast<const float4*>(D1 + qb);
            a00v += p0.x*d0.x + p0.y*d0.y + p0.z*d0.z + p0.w*d0.w;
            a01v += p0.x*d1.x + p0.y*d1.y + p0.z*d1.z + p0.w*d1.w;
            a10v += p1.x*d0.x + p1.y*d0.y + p1.z*d0.z + p1.w*d0.w;
            a11v += p1.x*d1.x + p1.y*d1.y + p1.z*d1.z + p1.w*d1.w;
        }
        float* so = sig + (size_t)b * F_PAD + 32;
        so[bc1 * 32 + bc2]               = a00v;
        so[bc1 * 32 + (bc2 + 16)]        = a01v;
        so[(bc1 + 16) * 32 + bc2]        = a10v;
        so[(bc1 + 16) * 32 + (bc2 + 16)] = a11v;
    }

    // level-1 + zero pad
    if (tid < 32) {
        const float* cr = colS + tid * 8;
        float s = cr[0] + cr[1] + cr[2] + cr[3] + cr[4] + cr[5] + cr[6];
        sig[(size_t)b * F_PAD + tid] = s;
    } else if (tid < 64) {
        sig[(size_t)b * F_PAD + F_SIG + (tid - 32)] = 0.f;
    }
}

// ---------- per-feature partial sum / sumsq (no atomics, no init, 8-row ILP) ----------
__global__ void k_stats(const float* __restrict__ sig, float* __restrict__ psum,
                        float* __restrict__ psq) {
    int f = blockIdx.x * 256 + threadIdx.x;
    if (f >= F_SIG) return;
    int y = blockIdx.y;
    const float* sp = sig + (size_t)(y * 64) * F_PAD + f;
    float s = 0.f, q = 0.f;
    for (int r = 0; r < 64; r += 8) {
        float v0 = sp[(size_t)(r + 0) * F_PAD];
        float v1 = sp[(size_t)(r + 1) * F_PAD];
        float v2 = sp[(size_t)(r + 2) * F_PAD];
        float v3 = sp[(size_t)(r + 3) * F_PAD];
        float v4 = sp[(size_t)(r + 4) * F_PAD];
        float v5 = sp[(size_t)(r + 5) * F_PAD];
        float v6 = sp[(size_t)(r + 6) * F_PAD];
        float v7 = sp[(size_t)(r + 7) * F_PAD];
        s += v0 + v1 + v2 + v3 + v4 + v5 + v6 + v7;
        q = fmaf(v0, v0, q); q = fmaf(v1, v1, q);
        q = fmaf(v2, v2, q); q = fmaf(v3, v3, q);
        q = fmaf(v4, v4, q); q = fmaf(v5, v5, q);
        q = fmaf(v6, v6, q); q = fmaf(v7, v7, q);
    }
    psum[(size_t)y * F_PAD + f] = s;
    psq[(size_t)y * F_PAD + f]  = q;
}

// ---------- reduce partials + inline BN fold; WfT + bias accumulation ----------
__launch_bounds__(64)
__global__ void k_wfred(const float* __restrict__ part,
                        const float* __restrict__ psum, const float* __restrict__ psq,
                        const float* __restrict__ gamma, const float* __restrict__ beta,
                        float* __restrict__ WfT, float* __restrict__ bfv) {
    const int i = blockIdx.x * 64 + threadIdx.x;
    const int k = blockIdx.y;
    float a = 0.f, bb = 0.f;
    if (i < F_SIG) {
        float s = 0.f, q = 0.f;
#pragma unroll
        for (int z = 0; z < SY; ++z) {
            s += psum[(size_t)z * F_PAD + i];
            q += psq[(size_t)z * F_PAD + i];
        }
        float m   = s * (1.f / 2048.f);
        float var = q * (1.f / 2048.f) - m * m;
        a  = gamma[i] / sqrtf(var + 1e-5f);
        bb = beta[i] - m * a;
    }
    const bool valid = (i < F_SIG) && (k < K_CLS);
    float s = 0.f;
    if (valid) {
#pragma unroll
        for (int z = 0; z < OSPLIT; ++z)
            s += part[((size_t)z * KW_PAD + k) * F_SIG + i];
    }
    if (i < F_SIG)
        WfT[(size_t)i * K_PAD + k] = valid ? a * s : 0.f;
    float pb = valid ? bb * s : 0.f;
#pragma unroll
    for (int d = 32; d; d >>= 1) pb += __shfl_xor(pb, d);
    if (threadIdx.x == 0 && k < K_CLS) atomicAdd(&bfv[k], pb);
}

// ---------- out[r,k]: 8 rows/block, waves split i-range; red aliases slT (33.8 KB LDS) ----------
__launch_bounds__(256, 4)
__global__ void k_out3(const float* __restrict__ sig, const float* __restrict__ WfT,
                       const float* __restrict__ bf, float* __restrict__ out) {
    __shared__ __align__(16) float slT[F_SIG * 8];   // [i][row]; later aliased as red[4096]
    const int tid = threadIdx.x;
    const int r0 = blockIdx.x * 8;
    for (int e = tid; e < 8 * (F_SIG / 4); e += 256) {
        int row = e & 7, c4 = e >> 3;
        float4 v = *reinterpret_cast<const float4*>(sig + (size_t)(r0 + row) * F_PAD + c4 * 4);
        slT[(c4 * 4 + 0) * 8 + row] = v.x;
        slT[(c4 * 4 + 1) * 8 + row] = v.y;
        slT[(c4 * 4 + 2) * 8 + row] = v.z;
        slT[(c4 * 4 + 3) * 8 + row] = v.w;
    }
    __syncthreads();

    const int wv = tid >> 6, lane = tid & 63;
    const int i0 = wv * 264;
    const float2* Wp = reinterpret_cast<const float2*>(WfT) + lane;
    float2 acc[8];
#pragma unroll
    for (int r = 0; r < 8; ++r) acc[r] = make_float2(0.f, 0.f);
    for (int g = 0; g < 33; ++g) {
        const int ib = i0 + g * 8;
        float2 w0 = Wp[(size_t)(ib + 0) * 64];
        float2 w1 = Wp[(size_t)(ib + 1) * 64];
        float2 w2 = Wp[(size_t)(ib + 2) * 64];
        float2 w3 = Wp[(size_t)(ib + 3) * 64];
        float2 w4 = Wp[(size_t)(ib + 4) * 64];
        float2 w5 = Wp[(size_t)(ib + 5) * 64];
        float2 w6 = Wp[(size_t)(ib + 6) * 64];
        float2 w7 = Wp[(size_t)(ib + 7) * 64];
#pragma unroll
        for (int j = 0; j < 8; ++j) {
            float2 wj = (j == 0) ? w0 : (j == 1) ? w1 : (j == 2) ? w2 : (j == 3) ? w3
                      : (j == 4) ? w4 : (j == 5) ? w5 : (j == 6) ? w6 : w7;
            const float4* sp = reinterpret_cast<const float4*>(slT + (ib + j) * 8);
            float4 ra = sp[0], rb = sp[1];
            acc[0].x = fmaf(ra.x, wj.x, acc[0].x); acc[0].y = fmaf(ra.x, wj.y, acc[0].y);
            acc[1].x = fmaf(ra.y, wj.x, acc[1].x); acc[1].y = fmaf(ra.y, wj.y, acc[1].y);
            acc[2].x = fmaf(ra.z, wj.x, acc[2].x); acc[2].y = fmaf(ra.z, wj.y, acc[2].y);
            acc[3].x = fmaf(ra.w, wj.x, acc[3].x); acc[3].y = fmaf(ra.w, wj.y, acc[3].y);
            acc[4].x = fmaf(rb.x, wj.x, acc[4].x); acc[4].y = fmaf(rb.x, wj.y, acc[4].y);
            acc[5].x = fmaf(rb.y, wj.x, acc[5].x); acc[5].y = fmaf(rb.y, wj.y, acc[5].y);
            acc[6].x = fmaf(rb.z, wj.x, acc[6].x); acc[6].y = fmaf(rb.z, wj.y, acc[6].y);
            acc[7].x = fmaf(rb.w, wj.x, acc[7].x); acc[7].y = fmaf(rb.w, wj.y, acc[7].y);
        }
    }
    __syncthreads();                      // all slT reads done -> safe to alias as red
    float* red = slT;
    float2* rp = reinterpret_cast<float2*>(red) + wv * 512 + lane;
#pragma unroll
    for (int r = 0; r < 8; ++r) rp[r * 64] = acc[r];
    __syncthreads();
#pragma unroll
    for (int j = 0; j < 4; ++j) {
        int idx = j * 256 + tid;
        int r = idx >> 7, k = idx & 127;
        float s = red[idx] + red[idx + 1024] + red[idx + 2048] + red[idx + 3072];
        if (k < K_CLS) out[(size_t)(r0 + r) * K_CLS + k] = s + bf[k];
    }
}

extern "C" void kernel_launch(void* const* d_in, const int* in_sizes, int n_in,
                              void* d_out, int out_size, void* d_ws, size_t ws_size,
                              hipStream_t stream) {
    (void)in_sizes; (void)n_in; (void)out_size; (void)ws_size;
    const float* feats = (const float*)d_in[0];
    const float* convw = (const float*)d_in[1];
    const float* gamma = (const float*)d_in[2];
    const float* beta  = (const float*)d_in[3];
    const float* linw  = (const float*)d_in[4];
    const float* linb  = (const float*)d_in[5];
    const float* fcw   = (const float*)d_in[6];
    const float* fcb   = (const float*)d_in[7];
    float* out = (float*)d_out;

    float* ws   = (float*)d_ws;
    float* sig  = ws;                                   // 2048*1088
    float* psum = sig + (size_t)N_B * F_PAD;            // 32*1088
    float* psq  = psum + (size_t)SY * F_PAD;            // 32*1088
    float* part = psq + (size_t)SY * F_PAD;             // 8*112*1056
    float* WfT  = part + (size_t)OSPLIT * KW_PAD * F_SIG;// 1056*128
    float* bfv  = WfT + (size_t)F_SIG * K_PAD;          // 128
    unsigned short* Ahi = (unsigned short*)(bfv + K_PAD);   // 36*512 ushort
    unsigned short* Alo = Ahi + 36 * 512;

    k_wt<<<72, 256, 0, stream>>>(convw, Ahi, Alo);
    k_fused<<<WF_BLKS + BF0_BLKS + N_B, 256, 0, stream>>>(feats, Ahi, Alo, sig,
                                                          fcw, linw, part, linb, fcb, bfv);
    k_stats<<<dim3(5, SY), 256, 0, stream>>>(sig, psum, psq);
    k_wfred<<<dim3(17, K_PAD), 64, 0, stream>>>(part, psum, psq, gamma, beta, WfT, bfv);
    k_out3<<<N_B / 8, 256, 0, stream>>>(sig, WfT, bfv, out);
}